// Round 2
// baseline (761.033 us; speedup 1.0000x reference)
//
#include <hip/hip_runtime.h>

#define LQ 1024
#define EMB 2048
#define NH 16
#define HD 128
#define RSCALE 0.022097086912079608f   /* 1/sqrt(2048) */
#define NEGS (-1e20f * RSCALE)         /* masked logit after scale */

// ---------------- K0: sin/cos tables (L x D) ----------------
__global__ __launch_bounds__(256) void k_sincos(float* __restrict__ cosT,
                                                float* __restrict__ sinT){
  int idx = blockIdx.x * 256 + threadIdx.x;       // < L*HD = 131072
  int l = idx >> 7, d = idx & 127, j = d & 63;
  float inv = 1.0f / powf(10000.0f, (float)(2 * j) * 0.0078125f);
  float ang = (float)l * inv;
  cosT[idx] = cosf(ang);
  sinT[idx] = sinf(ang);
}

// ---------------- K1: RoPE + per-head projection ----------------
// rows r = (n*L + l)*H + h over (32768 x 128) @ W^T(128x128)
// out layout: (n, h, l, d)
__global__ __launch_bounds__(256) void k_rope_proj(
    const float* __restrict__ vals,
    const float* __restrict__ keys,
    const float* __restrict__ qrys,
    const float* __restrict__ Wv,
    const float* __restrict__ Wk,
    const float* __restrict__ Wq,
    const float* __restrict__ cosT, const float* __restrict__ sinT,
    float* __restrict__ vp, float* __restrict__ kp, float* __restrict__ qp)
{
  __shared__ float Xs[64][132];
  __shared__ float Ws[32][132];
  int t = threadIdx.x;
  int which = blockIdx.y;
  const float* X; const float* W; float* OUT; bool rope;
  if (which == 0)      { X = vals; W = Wv; OUT = vp; rope = false; }
  else if (which == 1) { X = keys; W = Wk; OUT = kp; rope = true;  }
  else                 { X = qrys; W = Wq; OUT = qp; rope = true;  }
  int R0 = blockIdx.x * 64;

  // stage X tile, vectorized (2048 float4s)
  #pragma unroll
  for (int i = 0; i < 8; ++i) {
    int fi = t + 256 * i;
    int r = fi >> 5, dq = (fi & 31) * 4;
    *(float4*)&Xs[r][dq] = *(const float4*)&X[(size_t)(R0 + r) * HD + dq];
  }
  __syncthreads();

  // apply rope in-place (pairs d, 127-d)
  if (rope) {
    #pragma unroll
    for (int i = 0; i < 16; ++i) {
      int pi = t + 256 * i;            // < 4096 pairs
      int r = pi >> 6, d = pi & 63;
      int md = 127 - d;
      int l = ((R0 + r) >> 4) & 1023;
      float c0 = cosT[l * HD + d],  s0 = sinT[l * HD + d];
      float c1 = cosT[l * HD + md], s1 = sinT[l * HD + md];
      float x0 = Xs[r][d], x1 = Xs[r][md];
      Xs[r][d]  = x0 * c0 + x1 * s0;
      Xs[r][md] = x1 * c1 + x0 * s1;
    }
  }

  float acc[8][4];
  #pragma unroll
  for (int i = 0; i < 8; ++i)
    { acc[i][0] = 0.f; acc[i][1] = 0.f; acc[i][2] = 0.f; acc[i][3] = 0.f; }

  int ty = t >> 5, tx = t & 31;
  for (int k0 = 0; k0 < 128; k0 += 32) {
    __syncthreads();
    // stage Ws[kk][o] = W[o][k0+kk]
    {
      int o = t >> 1, kb = (t & 1) * 16;
      #pragma unroll
      for (int i = 0; i < 16; ++i)
        Ws[kb + i][o] = W[o * 128 + k0 + kb + i];
    }
    __syncthreads();
    #pragma unroll 4
    for (int kk = 0; kk < 32; ++kk) {
      float4 w = *(const float4*)&Ws[kk][tx * 4];
      #pragma unroll
      for (int i = 0; i < 8; ++i) {
        float a = Xs[ty * 8 + i][k0 + kk];
        acc[i][0] += a * w.x; acc[i][1] += a * w.y;
        acc[i][2] += a * w.z; acc[i][3] += a * w.w;
      }
    }
  }

  #pragma unroll
  for (int i = 0; i < 8; ++i) {
    int gr = R0 + ty * 8 + i;
    int n = gr >> 14;
    int l = (gr >> 4) & 1023;
    int h = gr & 15;
    size_t off = (((size_t)(n * NH + h)) * LQ + l) * HD + tx * 4;
    *(float4*)&OUT[off] = make_float4(acc[i][0], acc[i][1], acc[i][2], acc[i][3]);
  }
}

// ---------------- K2: flash attention (fp32) ----------------
__global__ __launch_bounds__(256) void k_attn(
    const float* __restrict__ qp, const float* __restrict__ kp,
    const float* __restrict__ vp, const int* __restrict__ mask,
    float* __restrict__ ao)
{
  __shared__ float Qs[64][132];
  __shared__ float Ks[32][132];
  __shared__ float Vs[32][132];
  __shared__ float Ss[64][33];
  __shared__ float mrow[64], lrow[64], arow[64];
  int t = threadIdx.x;
  int bh = blockIdx.y;           // n*NH + h
  int n = bh >> 4, h = bh & 15;
  int q0 = blockIdx.x * 64;
  const float* Q = qp + (size_t)bh * LQ * HD;
  const float* K = kp + (size_t)bh * LQ * HD;
  const float* V = vp + (size_t)bh * LQ * HD;
  const int* M = mask + (size_t)n * LQ * LQ;

  #pragma unroll
  for (int i = 0; i < 8; ++i) {
    int fi = t + 256 * i;        // < 2048 float4s
    int r = fi >> 5, dq = (fi & 31) * 4;
    *(float4*)&Qs[r][dq] = *(const float4*)&Q[(size_t)(q0 + r) * HD + dq];
  }
  if (t < 64) { mrow[t] = -INFINITY; lrow[t] = 0.f; }

  float acc_o[8][4];
  #pragma unroll
  for (int i = 0; i < 8; ++i)
    { acc_o[i][0]=0.f; acc_o[i][1]=0.f; acc_o[i][2]=0.f; acc_o[i][3]=0.f; }

  int tp = t >> 5, txp = t & 31;   // PV mapping: rows tp*8+i, cols txp*4
  int ty = t >> 4, tx = t & 15;    // S mapping: rows ty*4+i, cols tx*2+j

  for (int kt = 0; kt < 32; ++kt) {
    int k0 = kt * 32;
    __syncthreads();
    #pragma unroll
    for (int i = 0; i < 4; ++i) {
      int fi = t + 256 * i;      // < 1024
      int r = fi >> 5, dq = (fi & 31) * 4;
      *(float4*)&Ks[r][dq] = *(const float4*)&K[(size_t)(k0 + r) * HD + dq];
      *(float4*)&Vs[r][dq] = *(const float4*)&V[(size_t)(k0 + r) * HD + dq];
    }
    __syncthreads();

    // ---- S = Q K^T (rows ty*4+i, cols tx*2+{0,1}) ----
    float s[4][2];
    #pragma unroll
    for (int i = 0; i < 4; ++i) { s[i][0] = 0.f; s[i][1] = 0.f; }
    #pragma unroll 2
    for (int d = 0; d < 128; d += 4) {
      float4 ka = *(const float4*)&Ks[tx * 2][d];
      float4 kb = *(const float4*)&Ks[tx * 2 + 1][d];
      #pragma unroll
      for (int i = 0; i < 4; ++i) {
        float4 q = *(const float4*)&Qs[ty * 4 + i][d];
        s[i][0] += q.x * ka.x + q.y * ka.y + q.z * ka.z + q.w * ka.w;
        s[i][1] += q.x * kb.x + q.y * kb.y + q.z * kb.z + q.w * kb.w;
      }
    }
    // ---- mask, scale, online softmax ----
    #pragma unroll
    for (int i = 0; i < 4; ++i) {
      int qg = q0 + ty * 4 + i;
      int2 mm = *(const int2*)&M[(size_t)qg * LQ + k0 + tx * 2];
      s[i][0] = mm.x ? s[i][0] * RSCALE : NEGS;
      s[i][1] = mm.y ? s[i][1] * RSCALE : NEGS;
      float mx = fmaxf(s[i][0], s[i][1]);
      #pragma unroll
      for (int off = 8; off; off >>= 1) mx = fmaxf(mx, __shfl_xor(mx, off, 16));
      float mo = mrow[ty * 4 + i];
      float mn = fmaxf(mo, mx);
      float p0 = __expf(s[i][0] - mn), p1 = __expf(s[i][1] - mn);
      float ps = p0 + p1;
      #pragma unroll
      for (int off = 8; off; off >>= 1) ps += __shfl_xor(ps, off, 16);
      if (tx == 0) {
        float al = __expf(mo - mn);
        mrow[ty * 4 + i] = mn;
        arow[ty * 4 + i] = al;
        lrow[ty * 4 + i] = lrow[ty * 4 + i] * al + ps;
      }
      Ss[ty * 4 + i][tx * 2]     = p0;
      Ss[ty * 4 + i][tx * 2 + 1] = p1;
    }
    __syncthreads();
    // ---- O = O*alpha + P V ----
    #pragma unroll
    for (int i = 0; i < 8; ++i) {
      float al = arow[tp * 8 + i];
      acc_o[i][0] *= al; acc_o[i][1] *= al;
      acc_o[i][2] *= al; acc_o[i][3] *= al;
    }
    #pragma unroll 4
    for (int k = 0; k < 32; ++k) {
      float4 v = *(const float4*)&Vs[k][txp * 4];
      #pragma unroll
      for (int i = 0; i < 8; ++i) {
        float p = Ss[tp * 8 + i][k];
        acc_o[i][0] += p * v.x; acc_o[i][1] += p * v.y;
        acc_o[i][2] += p * v.z; acc_o[i][3] += p * v.w;
      }
    }
  }

  #pragma unroll
  for (int i = 0; i < 8; ++i) {
    int r = tp * 8 + i;
    float inv = 1.0f / lrow[r];
    size_t off = ((size_t)(n * LQ + q0 + r)) * EMB + h * HD + txp * 4;
    *(float4*)&ao[off] = make_float4(acc_o[i][0] * inv, acc_o[i][1] * inv,
                                     acc_o[i][2] * inv, acc_o[i][3] * inv);
  }
}

// ---------------- K3: output projection + bias ----------------
__global__ __launch_bounds__(256) void k_outproj(
    const float* __restrict__ ao, const float* __restrict__ Wo,
    const float* __restrict__ bo, float* __restrict__ out)
{
  __shared__ float As[64][36];
  __shared__ float Ws[32][132];
  int t = threadIdx.x;
  int m0 = blockIdx.x * 64, o0 = blockIdx.y * 128;
  int ty = t >> 5, tx = t & 31;
  float acc[8][4];
  #pragma unroll
  for (int i = 0; i < 8; ++i)
    { acc[i][0]=0.f; acc[i][1]=0.f; acc[i][2]=0.f; acc[i][3]=0.f; }

  for (int k0 = 0; k0 < EMB; k0 += 32) {
    __syncthreads();
    #pragma unroll
    for (int i = 0; i < 2; ++i) {
      int fi = t + 256 * i;      // < 512 float4s
      int r = fi >> 3, kq = (fi & 7) * 4;
      *(float4*)&As[r][kq] = *(const float4*)&ao[(size_t)(m0 + r) * EMB + k0 + kq];
    }
    {
      int o = t >> 1, kb = (t & 1) * 16;
      #pragma unroll
      for (int i = 0; i < 16; ++i)
        Ws[kb + i][o] = Wo[(size_t)(o0 + o) * EMB + k0 + kb + i];
    }
    __syncthreads();
    #pragma unroll 4
    for (int kk = 0; kk < 32; ++kk) {
      float4 w = *(const float4*)&Ws[kk][tx * 4];
      #pragma unroll
      for (int i = 0; i < 8; ++i) {
        float a = As[ty * 8 + i][kk];
        acc[i][0] += a * w.x; acc[i][1] += a * w.y;
        acc[i][2] += a * w.z; acc[i][3] += a * w.w;
      }
    }
  }

  float4 b = *(const float4*)&bo[o0 + tx * 4];
  #pragma unroll
  for (int i = 0; i < 8; ++i) {
    int m = m0 + ty * 8 + i;
    *(float4*)&out[(size_t)m * EMB + o0 + tx * 4] =
        make_float4(acc[i][0] + b.x, acc[i][1] + b.y,
                    acc[i][2] + b.z, acc[i][3] + b.w);
  }
}

extern "C" void kernel_launch(void* const* d_in, const int* in_sizes, int n_in,
                              void* d_out, int out_size, void* d_ws, size_t ws_size,
                              hipStream_t stream) {
  (void)in_sizes; (void)n_in; (void)out_size; (void)ws_size;
  const float* vals = (const float*)d_in[0];
  const float* keys = (const float*)d_in[1];
  const float* qrys = (const float*)d_in[2];
  const int*   mask = (const int*)d_in[3];
  const float* Wv   = (const float*)d_in[4];
  const float* Wk   = (const float*)d_in[5];
  const float* Wq   = (const float*)d_in[6];
  const float* Wo   = (const float*)d_in[7];
  const float* bo   = (const float*)d_in[8];
  float* out = (float*)d_out;

  float* ws   = (float*)d_ws;
  float* qp   = ws;                    // 4,194,304 floats (n,h,l,d)
  float* kp   = ws + 4194304;
  float* vp   = ws + 8388608;
  float* ao   = ws + 12582912;         // (n,l,e) fp32
  float* cosT = ws + 16777216;         // L*HD
  float* sinT = cosT + 131072;

  k_sincos  <<<dim3(512),     dim3(256), 0, stream>>>(cosT, sinT);
  k_rope_proj<<<dim3(512, 3), dim3(256), 0, stream>>>(vals, keys, qrys, Wv, Wk, Wq,
                                                      cosT, sinT, vp, kp, qp);
  k_attn    <<<dim3(16, 32),  dim3(256), 0, stream>>>(qp, kp, vp, mask, ao);
  k_outproj <<<dim3(32, 16),  dim3(256), 0, stream>>>(ao, Wo, bo, out);
}

// Round 3
// 351.223 us; speedup vs baseline: 2.1668x; 2.1668x over previous
//
#include <hip/hip_runtime.h>

#define LQ 1024
#define EMB 2048
#define NH 16
#define HD 128
#define RSCALE 0.022097086912079608f   /* 1/sqrt(2048) */
#define NEGS (-1e20f * RSCALE)         /* masked logit after scale */

typedef unsigned short u16x8 __attribute__((ext_vector_type(8)));
typedef __bf16 bf16x8 __attribute__((ext_vector_type(8)));
typedef float f32x4 __attribute__((ext_vector_type(4)));

__device__ __forceinline__ unsigned short f2b(float f){
  unsigned int x = __float_as_uint(f);
  return (unsigned short)((x + 0x7fffu + ((x >> 16) & 1u)) >> 16);
}
__device__ __forceinline__ bf16x8 as_bf(u16x8 u){
  union { u16x8 u; bf16x8 b; } c; c.u = u; return c.b;
}

// ---------------- K0: sin/cos tables (L x D) ----------------
__global__ __launch_bounds__(256) void k_sincos(float* __restrict__ cosT,
                                                float* __restrict__ sinT){
  int idx = blockIdx.x * 256 + threadIdx.x;       // < L*HD = 131072
  int l = idx >> 7, d = idx & 127, j = d & 63;
  float inv = 1.0f / powf(10000.0f, (float)(2 * j) * 0.0078125f);
  float ang = (float)l * inv;
  cosT[idx] = cosf(ang);
  sinT[idx] = sinf(ang);
}

// ---------------- K0b: fp32 -> bf16 convert (Wo) ----------------
__global__ __launch_bounds__(256) void k_cvt(const float* __restrict__ src,
                                             unsigned short* __restrict__ dst){
  int i = (blockIdx.x * 256 + threadIdx.x) * 4;
  float4 f = *(const float4*)&src[i];
  ushort4 u;
  u.x = f2b(f.x); u.y = f2b(f.y); u.z = f2b(f.z); u.w = f2b(f.w);
  *(ushort4*)&dst[i] = u;
}

// ---------------- K1: RoPE + per-head projection (fp32 compute, bf16 out) ----
// rows r = (n*L + l)*H + h over (32768 x 128) @ W^T(128x128); out (n,h,l,d) bf16
__global__ __launch_bounds__(256) void k_rope_proj(
    const float* __restrict__ vals,
    const float* __restrict__ keys,
    const float* __restrict__ qrys,
    const float* __restrict__ Wv,
    const float* __restrict__ Wk,
    const float* __restrict__ Wq,
    const float* __restrict__ cosT, const float* __restrict__ sinT,
    unsigned short* __restrict__ vp, unsigned short* __restrict__ kp,
    unsigned short* __restrict__ qp)
{
  __shared__ float Xs[64][132];
  __shared__ float Ws[32][132];
  int t = threadIdx.x;
  int which = blockIdx.y;
  const float* X; const float* W; unsigned short* OUT; bool rope;
  if (which == 0)      { X = vals; W = Wv; OUT = vp; rope = false; }
  else if (which == 1) { X = keys; W = Wk; OUT = kp; rope = true;  }
  else                 { X = qrys; W = Wq; OUT = qp; rope = true;  }
  int R0 = blockIdx.x * 64;

  #pragma unroll
  for (int i = 0; i < 8; ++i) {
    int fi = t + 256 * i;
    int r = fi >> 5, dq = (fi & 31) * 4;
    *(float4*)&Xs[r][dq] = *(const float4*)&X[(size_t)(R0 + r) * HD + dq];
  }
  __syncthreads();

  if (rope) {
    #pragma unroll
    for (int i = 0; i < 16; ++i) {
      int pi = t + 256 * i;            // < 4096 pairs
      int r = pi >> 6, d = pi & 63;
      int md = 127 - d;
      int l = ((R0 + r) >> 4) & 1023;
      float c0 = cosT[l * HD + d],  s0 = sinT[l * HD + d];
      float c1 = cosT[l * HD + md], s1 = sinT[l * HD + md];
      float x0 = Xs[r][d], x1 = Xs[r][md];
      Xs[r][d]  = x0 * c0 + x1 * s0;
      Xs[r][md] = x1 * c1 + x0 * s1;
    }
  }

  float acc[8][4];
  #pragma unroll
  for (int i = 0; i < 8; ++i)
    { acc[i][0] = 0.f; acc[i][1] = 0.f; acc[i][2] = 0.f; acc[i][3] = 0.f; }

  int ty = t >> 5, tx = t & 31;
  for (int k0 = 0; k0 < 128; k0 += 32) {
    __syncthreads();
    {
      int o = t >> 1, kb = (t & 1) * 16;
      #pragma unroll
      for (int i = 0; i < 16; ++i)
        Ws[kb + i][o] = W[o * 128 + k0 + kb + i];
    }
    __syncthreads();
    #pragma unroll 4
    for (int kk = 0; kk < 32; ++kk) {
      float4 w = *(const float4*)&Ws[kk][tx * 4];
      #pragma unroll
      for (int i = 0; i < 8; ++i) {
        float a = Xs[ty * 8 + i][k0 + kk];
        acc[i][0] += a * w.x; acc[i][1] += a * w.y;
        acc[i][2] += a * w.z; acc[i][3] += a * w.w;
      }
    }
  }

  #pragma unroll
  for (int i = 0; i < 8; ++i) {
    int gr = R0 + ty * 8 + i;
    int n = gr >> 14;
    int l = (gr >> 4) & 1023;
    int h = gr & 15;
    size_t off = (((size_t)(n * NH + h)) * LQ + l) * HD + tx * 4;
    ushort4 u;
    u.x = f2b(acc[i][0]); u.y = f2b(acc[i][1]);
    u.z = f2b(acc[i][2]); u.w = f2b(acc[i][3]);
    *(ushort4*)&OUT[off] = u;
  }
}

// ---------------- K2: MFMA flash attention (bf16 in, bf16 out) ----------------
// Bq=64 (4 waves x 16 rows), Bk=64. Q frags in registers; K row-major LDS;
// V transposed LDS; P via per-wave LDS; m/l/alpha in registers.
__global__ __launch_bounds__(256) void k_attn(
    const unsigned short* __restrict__ qp, const unsigned short* __restrict__ kp,
    const unsigned short* __restrict__ vp, const int* __restrict__ mask,
    unsigned short* __restrict__ ao)
{
  __shared__ unsigned short Ks[64 * 136];   // 17408 B, stride 272B (16|272)
  __shared__ unsigned short Vt[128 * 72];   // 18432 B, stride 144B (16|144)
  __shared__ unsigned short Ss[4 * 16 * 72];// 9216 B, per-wave 16x72
  int t = threadIdx.x;
  int w = t >> 6, lane = t & 63, quad = lane >> 4, n16 = lane & 15;
  int bh = blockIdx.y, nIdx = bh >> 4, h = bh & 15;
  int q0 = blockIdx.x * 64;
  size_t base = (size_t)bh * LQ * HD;
  const unsigned short* Q = qp + base;
  const unsigned short* K = kp + base;
  const unsigned short* V = vp + base;

  // Q fragments: A[m=n16][k=quad*8+j], 4 chunks of 32 along d
  bf16x8 qf[4];
  #pragma unroll
  for (int kd = 0; kd < 4; ++kd)
    qf[kd] = as_bf(*(const u16x8*)&Q[(size_t)(q0 + w * 16 + n16) * HD + kd * 32 + quad * 8]);

  const int* Mq[4];
  #pragma unroll
  for (int r = 0; r < 4; ++r)
    Mq[r] = mask + (size_t)nIdx * LQ * LQ + (size_t)(q0 + w * 16 + quad * 4 + r) * LQ + n16;

  f32x4 of[8];
  #pragma unroll
  for (int c = 0; c < 8; ++c) of[c] = (f32x4){0.f, 0.f, 0.f, 0.f};
  float m_r[4] = {-INFINITY, -INFINITY, -INFINITY, -INFINITY};
  float l_r[4] = {0.f, 0.f, 0.f, 0.f};

  unsigned short* Ssw = Ss + w * 16 * 72;
  int half = w & 1, kg = w >> 1;
  int dV = half * 64 + lane;               // d row this thread transposes

  for (int kt = 0; kt < 16; ++kt) {
    int k0 = kt * 64;
    __syncthreads();
    // stage K tile (64 x 128), coalesced 16B loads -> padded LDS rows
    #pragma unroll
    for (int i = 0; i < 4; ++i) {
      int li = t + 256 * i;
      int row = li >> 4, ch = li & 15;
      u16x8 v = *(const u16x8*)&K[(size_t)(k0 + row) * HD + ch * 8];
      *(u16x8*)&Ks[row * 136 + ch * 8] = v;
    }
    // stage V transposed: coalesced u16 row reads, packed b128 column writes
    #pragma unroll
    for (int p = 0; p < 4; ++p) {
      u16x8 pk;
      #pragma unroll
      for (int j = 0; j < 8; ++j)
        pk[j] = V[(size_t)(k0 + kg * 32 + p * 8 + j) * HD + dV];
      *(u16x8*)&Vt[dV * 72 + kg * 32 + p * 8] = pk;
    }
    __syncthreads();

    // ---- S = Q K^T : 4 col-frags x 4 d-steps ----
    f32x4 sf[4];
    #pragma unroll
    for (int c = 0; c < 4; ++c) sf[c] = (f32x4){0.f, 0.f, 0.f, 0.f};
    #pragma unroll
    for (int kd = 0; kd < 4; ++kd) {
      bf16x8 qv = qf[kd];
      #pragma unroll
      for (int c = 0; c < 4; ++c) {
        bf16x8 kv = as_bf(*(const u16x8*)&Ks[(c * 16 + n16) * 136 + kd * 32 + quad * 8]);
        sf[c] = __builtin_amdgcn_mfma_f32_16x16x32_bf16(qv, kv, sf[c], 0, 0, 0);
      }
    }

    // ---- mask + scale + online softmax (rows quad*4+r) ----
    float al[4];
    #pragma unroll
    for (int r = 0; r < 4; ++r) {
      float sv[4];
      #pragma unroll
      for (int c = 0; c < 4; ++c) {
        int mv = Mq[r][k0 + c * 16];
        sv[c] = mv ? sf[c][r] * RSCALE : NEGS;
      }
      float mx = fmaxf(fmaxf(sv[0], sv[1]), fmaxf(sv[2], sv[3]));
      #pragma unroll
      for (int off = 1; off < 16; off <<= 1) mx = fmaxf(mx, __shfl_xor(mx, off, 16));
      float mn = fmaxf(m_r[r], mx);
      al[r] = __expf(m_r[r] - mn);
      float ps = 0.f;
      #pragma unroll
      for (int c = 0; c < 4; ++c) {
        float p = __expf(sv[c] - mn);
        ps += p;
        Ssw[(quad * 4 + r) * 72 + c * 16 + n16] = f2b(p);
      }
      #pragma unroll
      for (int off = 1; off < 16; off <<= 1) ps += __shfl_xor(ps, off, 16);
      l_r[r] = l_r[r] * al[r] + ps;
      m_r[r] = mn;
    }
    // rescale O accumulators (same row<->reg mapping as S frags)
    #pragma unroll
    for (int c2 = 0; c2 < 8; ++c2) {
      #pragma unroll
      for (int r = 0; r < 4; ++r) of[c2][r] *= al[r];
    }
    // ---- O += P V : A=P from Ssw, B=V^T from Vt ----
    #pragma unroll
    for (int ks = 0; ks < 2; ++ks) {
      bf16x8 pv = as_bf(*(const u16x8*)&Ssw[n16 * 72 + ks * 32 + quad * 8]);
      #pragma unroll
      for (int c2 = 0; c2 < 8; ++c2) {
        bf16x8 vv = as_bf(*(const u16x8*)&Vt[(c2 * 16 + n16) * 72 + ks * 32 + quad * 8]);
        of[c2] = __builtin_amdgcn_mfma_f32_16x16x32_bf16(pv, vv, of[c2], 0, 0, 0);
      }
    }
  }

  float inv[4];
  #pragma unroll
  for (int r = 0; r < 4; ++r) inv[r] = 1.0f / l_r[r];
  #pragma unroll
  for (int c2 = 0; c2 < 8; ++c2) {
    #pragma unroll
    for (int r = 0; r < 4; ++r) {
      size_t off = ((size_t)(nIdx * LQ + q0 + w * 16 + quad * 4 + r)) * EMB
                 + h * HD + c2 * 16 + n16;
      ao[off] = f2b(of[c2][r] * inv[r]);
    }
  }
}

// ---------------- K3: output projection (bf16 MFMA) + bias, fp32 out --------
// tile 64(M) x 128(O), 4 waves each 64x32; BK=32
__global__ __launch_bounds__(256) void k_outproj(
    const unsigned short* __restrict__ ao, const unsigned short* __restrict__ Wob,
    const float* __restrict__ bo, float* __restrict__ out)
{
  __shared__ unsigned short As[64 * 40];    // stride 80B (16|80)
  __shared__ unsigned short Bs[128 * 40];
  int t = threadIdx.x;
  int w = t >> 6, lane = t & 63, quad = lane >> 4, n16 = lane & 15;
  int m0 = blockIdx.x * 64, o0 = blockIdx.y * 128;

  f32x4 of[4][2];
  #pragma unroll
  for (int a = 0; a < 4; ++a)
    { of[a][0] = (f32x4){0.f,0.f,0.f,0.f}; of[a][1] = (f32x4){0.f,0.f,0.f,0.f}; }

  for (int k0 = 0; k0 < EMB; k0 += 32) {
    __syncthreads();
    {
      int row = t >> 2, ch = t & 3;        // 64 x 4 chunks
      *(u16x8*)&As[row * 40 + ch * 8] =
          *(const u16x8*)&ao[(size_t)(m0 + row) * EMB + k0 + ch * 8];
    }
    #pragma unroll
    for (int i = 0; i < 2; ++i) {
      int li = t + 256 * i;                // 128 x 4 chunks
      int row = li >> 2, ch = li & 3;
      *(u16x8*)&Bs[row * 40 + ch * 8] =
          *(const u16x8*)&Wob[(size_t)(o0 + row) * EMB + k0 + ch * 8];
    }
    __syncthreads();
    bf16x8 af[4], bfr[2];
    #pragma unroll
    for (int a = 0; a < 4; ++a)
      af[a] = as_bf(*(const u16x8*)&As[(a * 16 + n16) * 40 + quad * 8]);
    #pragma unroll
    for (int b = 0; b < 2; ++b)
      bfr[b] = as_bf(*(const u16x8*)&Bs[(w * 32 + b * 16 + n16) * 40 + quad * 8]);
    #pragma unroll
    for (int a = 0; a < 4; ++a) {
      #pragma unroll
      for (int b = 0; b < 2; ++b)
        of[a][b] = __builtin_amdgcn_mfma_f32_16x16x32_bf16(af[a], bfr[b], of[a][b], 0, 0, 0);
    }
  }

  float bb[2] = { bo[o0 + w * 32 + n16], bo[o0 + w * 32 + 16 + n16] };
  #pragma unroll
  for (int a = 0; a < 4; ++a) {
    #pragma unroll
    for (int b = 0; b < 2; ++b) {
      #pragma unroll
      for (int r = 0; r < 4; ++r) {
        out[(size_t)(m0 + a * 16 + quad * 4 + r) * EMB + o0 + w * 32 + b * 16 + n16] =
            of[a][b][r] + bb[b];
      }
    }
  }
}

extern "C" void kernel_launch(void* const* d_in, const int* in_sizes, int n_in,
                              void* d_out, int out_size, void* d_ws, size_t ws_size,
                              hipStream_t stream) {
  (void)in_sizes; (void)n_in; (void)out_size; (void)ws_size;
  const float* vals = (const float*)d_in[0];
  const float* keys = (const float*)d_in[1];
  const float* qrys = (const float*)d_in[2];
  const int*   mask = (const int*)d_in[3];
  const float* Wv   = (const float*)d_in[4];
  const float* Wk   = (const float*)d_in[5];
  const float* Wq   = (const float*)d_in[6];
  const float* Wo   = (const float*)d_in[7];
  const float* bo   = (const float*)d_in[8];
  float* out = (float*)d_out;

  unsigned short* U  = (unsigned short*)d_ws;
  unsigned short* qp = U;                     // 4,194,304 bf16 each (n,h,l,d)
  unsigned short* kp = U + 4194304;
  unsigned short* vp = U + 8388608;
  unsigned short* ao = U + 12582912;          // (n,l,e) bf16
  unsigned short* Wob= U + 16777216;          // Wo as bf16
  float* cosT = (float*)(U + 20971520);       // L*HD fp32
  float* sinT = cosT + 131072;

  k_sincos   <<<dim3(512),     dim3(256), 0, stream>>>(cosT, sinT);
  k_cvt      <<<dim3(4096),    dim3(256), 0, stream>>>(Wo, Wob);
  k_rope_proj<<<dim3(512, 3),  dim3(256), 0, stream>>>(vals, keys, qrys, Wv, Wk, Wq,
                                                       cosT, sinT, vp, kp, qp);
  k_attn     <<<dim3(16, 32),  dim3(256), 0, stream>>>(qp, kp, vp, mask, ao);
  k_outproj  <<<dim3(32, 16),  dim3(256), 0, stream>>>(ao, Wob, bo, out);
}

// Round 4
// 223.479 us; speedup vs baseline: 3.4054x; 1.5716x over previous
//
#include <hip/hip_runtime.h>

#define LQ 1024
#define EMB 2048
#define NH 16
#define HD 128
#define RSCALE 0.022097086912079608f   /* 1/sqrt(2048) */

typedef unsigned short u16x8 __attribute__((ext_vector_type(8)));
typedef __bf16 bf16x8 __attribute__((ext_vector_type(8)));
typedef float f32x4 __attribute__((ext_vector_type(4)));

__device__ __forceinline__ unsigned short f2b(float f){
  unsigned int x = __float_as_uint(f);
  return (unsigned short)((x + 0x7fffu + ((x >> 16) & 1u)) >> 16);
}
__device__ __forceinline__ bf16x8 as_bf(u16x8 u){
  union { u16x8 u; bf16x8 b; } c; c.u = u; return c.b;
}

// ---------------- K0: sin/cos tables (L x D) ----------------
__global__ __launch_bounds__(256) void k_sincos(float* __restrict__ cosT,
                                                float* __restrict__ sinT){
  int idx = blockIdx.x * 256 + threadIdx.x;       // < L*HD = 131072
  int l = idx >> 7, d = idx & 127, j = d & 63;
  float inv = 1.0f / powf(10000.0f, (float)(2 * j) * 0.0078125f);
  float ang = (float)l * inv;
  cosT[idx] = cosf(ang);
  sinT[idx] = sinf(ang);
}

// ---------------- K0b: fp32 -> bf16 convert (Wo) ----------------
__global__ __launch_bounds__(256) void k_cvt(const float* __restrict__ src,
                                             unsigned short* __restrict__ dst){
  int i = (blockIdx.x * 256 + threadIdx.x) * 4;
  float4 f = *(const float4*)&src[i];
  ushort4 u;
  u.x = f2b(f.x); u.y = f2b(f.y); u.z = f2b(f.z); u.w = f2b(f.w);
  *(ushort4*)&dst[i] = u;
}

// ---------------- K0c: pack mask to bits (one u64 per wave via ballot) ------
__global__ __launch_bounds__(256) void k_maskpack(const int* __restrict__ M,
                                                  unsigned long long* __restrict__ Mb){
  int w_idx = blockIdx.x * 4 + (threadIdx.x >> 6);   // < 32768
  int lane = threadIdx.x & 63;
  int n = w_idx >> 14, row = (w_idx >> 4) & 1023, wc = w_idx & 15;
  int v = M[(size_t)n * (LQ * LQ) + (size_t)row * LQ + wc * 64 + lane];
  unsigned long long b = __ballot(v != 0);
  if (lane == 0) Mb[w_idx] = b;
}

// ---------------- K1: RoPE (fused in staging) + projection, bf16 MFMA -------
// C[m=(n*L+l)*H+h][o] = rope(X)[m] @ W^T ; out (n,h,l,d) bf16
__global__ __launch_bounds__(256) void k_proj(
    const float* __restrict__ vals, const float* __restrict__ keys,
    const float* __restrict__ qrys,
    const float* __restrict__ Wv, const float* __restrict__ Wk,
    const float* __restrict__ Wq,
    const float* __restrict__ cosT, const float* __restrict__ sinT,
    unsigned short* __restrict__ vp, unsigned short* __restrict__ kp,
    unsigned short* __restrict__ qp)
{
  __shared__ unsigned short Xs[64 * 136];
  __shared__ unsigned short Ws[128 * 136];
  int t = threadIdx.x;
  int which = blockIdx.y;
  const float* X; const float* W; unsigned short* OUT; bool rope;
  if (which == 0)      { X = vals; W = Wv; OUT = vp; rope = false; }
  else if (which == 1) { X = keys; W = Wk; OUT = kp; rope = true;  }
  else                 { X = qrys; W = Wq; OUT = qp; rope = true;  }
  int m0 = blockIdx.x * 64;

  // stage W -> bf16 LDS (rows = o, cols = d)
  #pragma unroll
  for (int i = 0; i < 8; ++i) {
    int ci = t + 256 * i;                 // 2048 chunks of 8
    int row = ci >> 4, ch = ci & 15;
    float4 a = *(const float4*)&W[row * 128 + ch * 8];
    float4 b = *(const float4*)&W[row * 128 + ch * 8 + 4];
    u16x8 u;
    u[0]=f2b(a.x); u[1]=f2b(a.y); u[2]=f2b(a.z); u[3]=f2b(a.w);
    u[4]=f2b(b.x); u[5]=f2b(b.y); u[6]=f2b(b.z); u[7]=f2b(b.w);
    *(u16x8*)&Ws[row * 136 + ch * 8] = u;
  }
  // stage X tile with rope -> bf16 LDS
  #pragma unroll
  for (int i = 0; i < 8; ++i) {
    int fi = t + 256 * i;                 // 2048 float4 groups
    int row = fi >> 5, dq = (fi & 31) * 4;
    int gr = m0 + row;
    float4 x = *(const float4*)&X[(size_t)gr * HD + dq];
    ushort4 u;
    if (rope) {
      int l = (gr >> 4) & 1023;
      float4 xm = *(const float4*)&X[(size_t)gr * HD + (124 - dq)];
      float4 c  = *(const float4*)&cosT[l * HD + dq];
      float4 s  = *(const float4*)&sinT[l * HD + dq];
      u.x = f2b(x.x * c.x + xm.w * s.x);
      u.y = f2b(x.y * c.y + xm.z * s.y);
      u.z = f2b(x.z * c.z + xm.y * s.z);
      u.w = f2b(x.w * c.w + xm.x * s.w);
    } else {
      u.x = f2b(x.x); u.y = f2b(x.y); u.z = f2b(x.z); u.w = f2b(x.w);
    }
    *(ushort4*)&Xs[row * 136 + dq] = u;
  }
  __syncthreads();

  int w = t >> 6, lane = t & 63, quad = lane >> 4, n16 = lane & 15;
  f32x4 of[4][2];
  #pragma unroll
  for (int a = 0; a < 4; ++a)
    { of[a][0] = (f32x4){0.f,0.f,0.f,0.f}; of[a][1] = (f32x4){0.f,0.f,0.f,0.f}; }

  #pragma unroll
  for (int kd = 0; kd < 4; ++kd) {
    bf16x8 bfr[2];
    #pragma unroll
    for (int b2 = 0; b2 < 2; ++b2)
      bfr[b2] = as_bf(*(const u16x8*)&Ws[(w * 32 + b2 * 16 + n16) * 136 + kd * 32 + quad * 8]);
    #pragma unroll
    for (int a = 0; a < 4; ++a) {
      bf16x8 af = as_bf(*(const u16x8*)&Xs[(a * 16 + n16) * 136 + kd * 32 + quad * 8]);
      of[a][0] = __builtin_amdgcn_mfma_f32_16x16x32_bf16(af, bfr[0], of[a][0], 0, 0, 0);
      of[a][1] = __builtin_amdgcn_mfma_f32_16x16x32_bf16(af, bfr[1], of[a][1], 0, 0, 0);
    }
  }

  #pragma unroll
  for (int a = 0; a < 4; ++a) {
    #pragma unroll
    for (int b2 = 0; b2 < 2; ++b2) {
      #pragma unroll
      for (int r = 0; r < 4; ++r) {
        int m = m0 + a * 16 + quad * 4 + r;
        int n = m >> 14, l = (m >> 4) & 1023, h = m & 15;
        int o = w * 32 + b2 * 16 + n16;
        OUT[(((size_t)(n * NH + h)) * LQ + l) * HD + o] = f2b(of[a][b2][r]);
      }
    }
  }
}

// ---------------- K1b: transpose V (n,h,l,d) -> (n,h,d,l) ----------------
__global__ __launch_bounds__(256) void k_vtrans(const unsigned short* __restrict__ vp,
                                                unsigned short* __restrict__ vt){
  __shared__ unsigned short Ls[64 * 136];
  int t = threadIdx.x;
  int l0 = blockIdx.x * 64;
  size_t base = (size_t)blockIdx.y * LQ * HD;     // nh
  #pragma unroll
  for (int i = 0; i < 4; ++i) {
    int ci = t + 256 * i;                 // 1024 chunks
    int row = ci >> 4, ch = ci & 15;
    *(u16x8*)&Ls[row * 136 + ch * 8] =
        *(const u16x8*)&vp[base + (size_t)(l0 + row) * HD + ch * 8];
  }
  __syncthreads();
  #pragma unroll
  for (int i = 0; i < 4; ++i) {
    int idx = t + 256 * i;
    int d = idx & 127, lc = idx >> 7;     // conflict-free gather (d across lanes)
    u16x8 pk;
    #pragma unroll
    for (int j = 0; j < 8; ++j) pk[j] = Ls[(lc * 8 + j) * 136 + d];
    *(u16x8*)&vt[base + (size_t)d * LQ + l0 + lc * 8] = pk;
  }
}

// ---------------- K2: MFMA flash attention, no-max softmax ----------------
// Bq=64 (4 waves x 16 q-rows), Bk=64; K row-major LDS; V^T LDS from vt;
// bitmask; register-double-buffered staging; l-reduction deferred to end.
__global__ __launch_bounds__(256) void k_attn(
    const unsigned short* __restrict__ qp, const unsigned short* __restrict__ kp,
    const unsigned short* __restrict__ vt, const unsigned long long* __restrict__ Mb,
    unsigned short* __restrict__ ao)
{
  __shared__ unsigned short Ks[64 * 136];
  __shared__ unsigned short Vt[128 * 72];
  __shared__ unsigned short Ss[4 * 16 * 72];
  int t = threadIdx.x, w = t >> 6, lane = t & 63, quad = lane >> 4, n16 = lane & 15;
  int bh = blockIdx.y, nIdx = bh >> 4, h = bh & 15;
  int q0 = blockIdx.x * 64;
  size_t base = (size_t)bh * LQ * HD;
  const unsigned short* Q = qp + base;
  const unsigned short* K = kp + base;
  const unsigned short* V = vt + base;            // (d, l)

  bf16x8 qf[4];
  #pragma unroll
  for (int kd = 0; kd < 4; ++kd)
    qf[kd] = as_bf(*(const u16x8*)&Q[(size_t)(q0 + w * 16 + n16) * HD + kd * 32 + quad * 8]);

  const unsigned long long* MbRow =
      Mb + ((size_t)nIdx * LQ + q0 + w * 16 + quad * 4) * 16;

  f32x4 of[8];
  #pragma unroll
  for (int c = 0; c < 8; ++c) of[c] = (f32x4){0.f, 0.f, 0.f, 0.f};
  float lp[4] = {0.f, 0.f, 0.f, 0.f};
  unsigned short* Ssw = Ss + w * 1152;

  // prefetch tile 0 into registers
  u16x8 pk[4], pv[4];
  #pragma unroll
  for (int i = 0; i < 4; ++i) {
    int ci = t + 256 * i;
    pk[i] = *(const u16x8*)&K[(size_t)(ci >> 4) * HD + (ci & 15) * 8];
    pv[i] = *(const u16x8*)&V[(size_t)(ci >> 3) * LQ + (ci & 7) * 8];
  }

  for (int kt = 0; kt < 16; ++kt) {
    __syncthreads();
    #pragma unroll
    for (int i = 0; i < 4; ++i) {
      int ci = t + 256 * i;
      *(u16x8*)&Ks[(ci >> 4) * 136 + (ci & 15) * 8] = pk[i];
      *(u16x8*)&Vt[(ci >> 3) * 72 + (ci & 7) * 8]  = pv[i];
    }
    __syncthreads();
    if (kt < 15) {
      int k1 = (kt + 1) * 64;
      #pragma unroll
      for (int i = 0; i < 4; ++i) {
        int ci = t + 256 * i;
        pk[i] = *(const u16x8*)&K[(size_t)(k1 + (ci >> 4)) * HD + (ci & 15) * 8];
        pv[i] = *(const u16x8*)&V[(size_t)(ci >> 3) * LQ + k1 + (ci & 7) * 8];
      }
    }
    unsigned long long mw[4];
    #pragma unroll
    for (int r = 0; r < 4; ++r) mw[r] = MbRow[r * 16 + kt];

    // ---- S = Q K^T ----
    f32x4 sf[4];
    #pragma unroll
    for (int c = 0; c < 4; ++c) sf[c] = (f32x4){0.f, 0.f, 0.f, 0.f};
    #pragma unroll
    for (int kd = 0; kd < 4; ++kd) {
      #pragma unroll
      for (int c = 0; c < 4; ++c) {
        bf16x8 kv = as_bf(*(const u16x8*)&Ks[(c * 16 + n16) * 136 + kd * 32 + quad * 8]);
        sf[c] = __builtin_amdgcn_mfma_f32_16x16x32_bf16(qf[kd], kv, sf[c], 0, 0, 0);
      }
    }
    // ---- no-max softmax: p = bit ? exp(s*scale) : 0 ----
    #pragma unroll
    for (int r = 0; r < 4; ++r) {
      #pragma unroll
      for (int c = 0; c < 4; ++c) {
        int bit = (int)((mw[r] >> (c * 16 + n16)) & 1ull);
        float p = bit ? __expf(sf[c][r] * RSCALE) : 0.f;
        lp[r] += p;
        Ssw[(quad * 4 + r) * 72 + c * 16 + n16] = f2b(p);
      }
    }
    // ---- O += P V ----
    #pragma unroll
    for (int ks = 0; ks < 2; ++ks) {
      bf16x8 pa = as_bf(*(const u16x8*)&Ssw[n16 * 72 + ks * 32 + quad * 8]);
      #pragma unroll
      for (int c2 = 0; c2 < 8; ++c2) {
        bf16x8 vv = as_bf(*(const u16x8*)&Vt[(c2 * 16 + n16) * 72 + ks * 32 + quad * 8]);
        of[c2] = __builtin_amdgcn_mfma_f32_16x16x32_bf16(pa, vv, of[c2], 0, 0, 0);
      }
    }
  }

  // deferred l reduction (within 16-lane groups = fixed quad)
  #pragma unroll
  for (int r = 0; r < 4; ++r) {
    float s = lp[r];
    #pragma unroll
    for (int off = 1; off < 16; off <<= 1) s += __shfl_xor(s, off, 16);
    lp[r] = 1.0f / fmaxf(s, 1e-30f);
  }
  #pragma unroll
  for (int c2 = 0; c2 < 8; ++c2) {
    #pragma unroll
    for (int r = 0; r < 4; ++r) {
      ao[((size_t)(nIdx * LQ + q0 + w * 16 + quad * 4 + r)) * EMB + h * HD + c2 * 16 + n16] =
          f2b(of[c2][r] * lp[r]);
    }
  }
}

// ---------------- K3: output projection (bf16 MFMA) + bias, fp32 out --------
__global__ __launch_bounds__(256) void k_outproj(
    const unsigned short* __restrict__ ao, const unsigned short* __restrict__ Wob,
    const float* __restrict__ bo, float* __restrict__ out)
{
  __shared__ unsigned short As[64 * 40];
  __shared__ unsigned short Bs[128 * 40];
  int t = threadIdx.x;
  int w = t >> 6, lane = t & 63, quad = lane >> 4, n16 = lane & 15;
  int m0 = blockIdx.x * 64, o0 = blockIdx.y * 128;

  f32x4 of[4][2];
  #pragma unroll
  for (int a = 0; a < 4; ++a)
    { of[a][0] = (f32x4){0.f,0.f,0.f,0.f}; of[a][1] = (f32x4){0.f,0.f,0.f,0.f}; }

  for (int k0 = 0; k0 < EMB; k0 += 32) {
    __syncthreads();
    {
      int row = t >> 2, ch = t & 3;
      *(u16x8*)&As[row * 40 + ch * 8] =
          *(const u16x8*)&ao[(size_t)(m0 + row) * EMB + k0 + ch * 8];
    }
    #pragma unroll
    for (int i = 0; i < 2; ++i) {
      int li = t + 256 * i;
      int row = li >> 2, ch = li & 3;
      *(u16x8*)&Bs[row * 40 + ch * 8] =
          *(const u16x8*)&Wob[(size_t)(o0 + row) * EMB + k0 + ch * 8];
    }
    __syncthreads();
    bf16x8 af[4], bfr[2];
    #pragma unroll
    for (int a = 0; a < 4; ++a)
      af[a] = as_bf(*(const u16x8*)&As[(a * 16 + n16) * 40 + quad * 8]);
    #pragma unroll
    for (int b = 0; b < 2; ++b)
      bfr[b] = as_bf(*(const u16x8*)&Bs[(w * 32 + b * 16 + n16) * 40 + quad * 8]);
    #pragma unroll
    for (int a = 0; a < 4; ++a) {
      #pragma unroll
      for (int b = 0; b < 2; ++b)
        of[a][b] = __builtin_amdgcn_mfma_f32_16x16x32_bf16(af[a], bfr[b], of[a][b], 0, 0, 0);
    }
  }

  float bb[2] = { bo[o0 + w * 32 + n16], bo[o0 + w * 32 + 16 + n16] };
  #pragma unroll
  for (int a = 0; a < 4; ++a) {
    #pragma unroll
    for (int b = 0; b < 2; ++b) {
      #pragma unroll
      for (int r = 0; r < 4; ++r) {
        out[(size_t)(m0 + a * 16 + quad * 4 + r) * EMB + o0 + w * 32 + b * 16 + n16] =
            of[a][b][r] + bb[b];
      }
    }
  }
}

extern "C" void kernel_launch(void* const* d_in, const int* in_sizes, int n_in,
                              void* d_out, int out_size, void* d_ws, size_t ws_size,
                              hipStream_t stream) {
  (void)in_sizes; (void)n_in; (void)out_size; (void)ws_size;
  const float* vals = (const float*)d_in[0];
  const float* keys = (const float*)d_in[1];
  const float* qrys = (const float*)d_in[2];
  const int*   mask = (const int*)d_in[3];
  const float* Wv   = (const float*)d_in[4];
  const float* Wk   = (const float*)d_in[5];
  const float* Wq   = (const float*)d_in[6];
  const float* Wo   = (const float*)d_in[7];
  const float* bo   = (const float*)d_in[8];
  float* out = (float*)d_out;

  unsigned short* U  = (unsigned short*)d_ws;
  unsigned short* qp = U;                              // (n,h,l,d) bf16
  unsigned short* kp = U + 4194304;
  unsigned short* vp = U + 8388608;
  unsigned short* vt = U + 12582912;                   // (n,h,d,l) bf16
  unsigned short* ao = U + 16777216;                   // (n,l,e) bf16
  unsigned short* Wob= U + 20971520;                   // Wo bf16
  unsigned long long* Mb = (unsigned long long*)(U + 25165824);  // 32768 u64
  float* cosT = (float*)(U + 25296896);
  float* sinT = cosT + 131072;

  k_sincos  <<<dim3(512),    dim3(256), 0, stream>>>(cosT, sinT);
  k_cvt     <<<dim3(4096),   dim3(256), 0, stream>>>(Wo, Wob);
  k_maskpack<<<dim3(8192),   dim3(256), 0, stream>>>(mask, Mb);
  k_proj    <<<dim3(512, 3), dim3(256), 0, stream>>>(vals, keys, qrys, Wv, Wk, Wq,
                                                     cosT, sinT, vp, kp, qp);
  k_vtrans  <<<dim3(16, 32), dim3(256), 0, stream>>>(vp, vt);
  k_attn    <<<dim3(16, 32), dim3(256), 0, stream>>>(qp, kp, vt, Mb, ao);
  k_outproj <<<dim3(32, 16), dim3(256), 0, stream>>>(ao, Wob, bo, out);
}